// Round 15
// baseline (284.646 us; speedup 1.0000x reference)
//
#include <hip/hip_runtime.h>
#include <cstdint>
#include <cstddef>

// ---------------- problem constants ----------------
#define B_    64
#define N_    197
#define DIM_  768
#define NH_   12
#define HD_   64
#define NP_   196
#define SCALE_ 0.125f
#define EPS_   1.1920929e-07f
#define BN_EPS_ 1e-5f
#define ALPHA_ 0.01f

#define M_TOK   (B_*N_)        // 12608
#define M_PATCH (B_*NP_)       // 12544
#define OUT_MAIN (M_TOK*DIM_)  // 9682944

#define K2_  768               // qkv GEMM K (bf16)
#define NT_  24                // K2_/32
#define K2P_ 896               // proj GEMM K = 768 (msa) + 128 (act13)
#define NTP_ 28                // K2P_/32

// scalar workspace layout (float offsets within SC)
#define W_OFF     0
#define HP_OFF    16
#define HPROW_OFF 128
#define NVB_OFF   144
#define SVB_OFF   720
#define STATS_OFF 784          // 256 floats: sc1,off1,sc3,off3
#define SC_FLOATS 132096

typedef short bf16x8_ __attribute__((ext_vector_type(8)));
typedef float f32x4_  __attribute__((ext_vector_type(4)));

// ---------------- prep ----------------
__global__ void prep_kernel(const float* __restrict__ uniforms, const float* __restrict__ kth,
                            const float* __restrict__ head_probs, const float* __restrict__ v_b,
                            float* __restrict__ SC, float* __restrict__ out_tail)
{
    int t = threadIdx.x;
    if (t == 0) {
        float ind[3];
        for (int i = 0; i < 3; i++) {
            float s = 1.f/(1.f + expf(-kth[i]));
            float p = fminf(fmaxf(s, EPS_), 1.f - EPS_);
            float u = fminf(fmaxf(uniforms[i], EPS_), 1.f - EPS_);
            float logit = logf(u) - log1pf(-u) + logf(p) - log1pf(-p);
            ind[i] = (logit > 0.f) ? 1.f : 0.f;
        }
        SC[W_OFF+0] = ind[2];
        SC[W_OFF+1] = ind[1]*(1.f-ind[2]);
        SC[W_OFF+2] = ind[0]*(1.f-ind[1])*(1.f-ind[2]);
        float kprod = 1.f;
        for (int i = 0; i < 3; i++) {
            float ktv = 1.f/(1.f + expf(-kth[i]));
            kprod *= (ktv > 0.5f) ? 1.f : 0.f;
            out_tail[i]   = kprod;
            out_tail[3+i] = ktv;
        }
    }
    if (t < 9) {
        float mx = -1e30f;
        for (int h = 0; h < 12; h++) mx = fmaxf(mx, head_probs[h*9+t]);
        float e[12]; float s = 0.f;
        for (int h = 0; h < 12; h++) { e[h] = expf((head_probs[h*9+t]-mx)/ALPHA_); s += e[h]; }
        for (int h = 0; h < 12; h++) SC[HP_OFF + h*9 + t] = e[h]/s;
    }
    __syncthreads();
    if (t < 12) {
        float s = 0.f;
        for (int k = 0; k < 9; k++) s += SC[HP_OFF + t*9 + k];
        SC[HPROW_OFF + t] = s;
    }
    if (t < 64) {
        float sv = 0.f;
        for (int k = 0; k < 9; k++) {
            float s = 0.f;
            for (int h = 0; h < 12; h++) s += v_b[h*64+t]*SC[HP_OFF + h*9 + k];
            SC[NVB_OFF + t*9 + k] = s;
            sv += s;
        }
        SC[SVB_OFF + t] = sv;
    }
}

// ---------------- fp32 -> bf16 (RNE) ----------------
__device__ __forceinline__ unsigned short bfr_(float f) {
    unsigned u = __float_as_uint(f);
    return (unsigned short)((u + 0x7FFFu + ((u >> 16) & 1u)) >> 16);
}
__device__ __forceinline__ float bf2f_(unsigned short u) {
    return __uint_as_float((unsigned)u << 16);
}

// single fused conversion for x, qk_w, v_w
__global__ __launch_bounds__(256) void conv_all(
    const float* __restrict__ x, const float* __restrict__ qkw, const float* __restrict__ vw,
    unsigned int* __restrict__ x2, unsigned int* __restrict__ W2a, unsigned int* __restrict__ W2b)
{
    int i = blockIdx.x*256 + threadIdx.x;
    const float* src; unsigned int* dst; int off;
    if (i < 1210368)      { src = x;   dst = x2;  off = i; }
    else if (i < 1357824) { src = qkw; dst = W2a; off = i - 1210368; }
    else if (i < 1431552) { src = vw;  dst = W2b; off = i - 1357824; }
    else return;
    float4 a = ((const float4*)src)[2*off];
    float4 b = ((const float4*)src)[2*off+1];
    unsigned r0 = (unsigned)bfr_(a.x) | ((unsigned)bfr_(a.y) << 16);
    unsigned r1 = (unsigned)bfr_(a.z) | ((unsigned)bfr_(a.w) << 16);
    unsigned r2 = (unsigned)bfr_(b.x) | ((unsigned)bfr_(b.y) << 16);
    unsigned r3 = (unsigned)bfr_(b.z) | ((unsigned)bfr_(b.w) << 16);
    ((uint4*)dst)[off] = make_uint4(r0, r1, r2, r3);
}

// ---- global_load_lds staging (linear [128][32] ushorts; per-lane XOR src, XOR read) ----
#define STAGE_TILE2(LDSPTR, GBASE, ROWCLAMP, KOFF, STRIDE)                               \
    {                                                                                    \
        _Pragma("unroll")                                                                \
        for (int i_ = 0; i_ < 2; i_++) {                                                 \
            int r_ = wave*32 + i_*16 + (lane >> 2);                                      \
            int gr_ = ROWCLAMP(r_);                                                      \
            const unsigned short* gp_ = (GBASE) + (size_t)gr_*(STRIDE) + (KOFF)          \
                                        + (((lane & 3) ^ (r_ & 3)) * 8);                 \
            __builtin_amdgcn_global_load_lds(                                            \
                (const __attribute__((address_space(1))) unsigned int*)gp_,              \
                (__attribute__((address_space(3))) unsigned int*)&(LDSPTR)[(wave*32 + i_*16)*32], \
                16, 0, 0);                                                               \
        }                                                                                \
    }

// end-of-iter fence: wait next-tile loads complete (MFMA already covered latency), barrier
#define BAR_VM0()  asm volatile("s_waitcnt vmcnt(0)\n\ts_barrier" ::: "memory")

// ---------------- merged qk+v GEMM (bf16 MFMA, minimum-2-phase: stage-first, 1 barrier/iter) ----
__global__ __launch_bounds__(256) void gemm_qkv(
    const unsigned short* __restrict__ A2, const unsigned short* __restrict__ W2,
    const float* __restrict__ qk_b,
    unsigned short* __restrict__ qkbf, unsigned short* __restrict__ vbf,
    unsigned short* __restrict__ vbfT)
{
    __shared__ unsigned short At[2][128*32];
    __shared__ unsigned short Bt[2][128*32];
    const int nwg = 1782;
    int q = nwg >> 3, rr = nwg & 7;
    int xcd = blockIdx.x & 7, idx = blockIdx.x >> 3;
    int s = (xcd < rr) ? xcd*(q+1) + idx : rr*(q+1) + (xcd - rr)*q + idx;
    const int n0 = (s % 18) * 128, m0 = (s / 18) * 128;
    const int tid = threadIdx.x;
    const int wave = tid >> 6, lane = tid & 63;
    const int wr = (wave >> 1)*64, wc = (wave & 1)*64;
    const int fr = lane & 15, fq = lane >> 4;
    const int xk = (fq ^ (fr & 3)) * 8;

    f32x4_ acc[4][4] = {};

    #define CLA_(r) ((m0 + (r) < M_TOK) ? (m0 + (r)) : (M_TOK-1))
    #define CLB_(r) (n0 + (r))
    STAGE_TILE2(At[0], A2, CLA_, 0, K2_)
    STAGE_TILE2(Bt[0], W2, CLB_, 0, K2_)
    BAR_VM0();
    for (int kt = 0; kt < NT_; kt++) {
        const int cur = kt & 1;
        if (kt + 1 < NT_) {
            STAGE_TILE2(At[cur^1], A2, CLA_, (kt+1)*32, K2_)
            STAGE_TILE2(Bt[cur^1], W2, CLB_, (kt+1)*32, K2_)
        }
        bf16x8_ a[4], bb[4];
        #pragma unroll
        for (int i = 0; i < 4; i++) {
            a[i]  = *(const bf16x8_*)&At[cur][(wr + i*16 + fr)*32 + xk];
            bb[i] = *(const bf16x8_*)&Bt[cur][(wc + i*16 + fr)*32 + xk];
        }
        __builtin_amdgcn_s_setprio(1);
        #pragma unroll
        for (int mi = 0; mi < 4; mi++)
            #pragma unroll
            for (int ni = 0; ni < 4; ni++)
                acc[mi][ni] = __builtin_amdgcn_mfma_f32_16x16x32_bf16(a[mi], bb[ni], acc[mi][ni], 0, 0, 0);
        __builtin_amdgcn_s_setprio(0);
        if (kt + 1 < NT_) BAR_VM0();
    }
    #undef CLA_
    #undef CLB_

    if (n0 < 1536) {
        float bv[4];
        #pragma unroll
        for (int ni = 0; ni < 4; ni++) bv[ni] = qk_b[n0 + wc + ni*16 + fr];
        #pragma unroll
        for (int mi = 0; mi < 4; mi++) {
            #pragma unroll
            for (int j = 0; j < 4; j++) {
                int row = m0 + wr + mi*16 + fq*4 + j;
                if (row < M_TOK) {
                    unsigned short* crow = qkbf + (size_t)row*1536 + n0 + wc;
                    #pragma unroll
                    for (int ni = 0; ni < 4; ni++)
                        crow[ni*16 + fr] = bfr_(acc[mi][ni][j] + bv[ni]);
                }
            }
        }
    } else {
        const int v0 = n0 - 1536;
        #pragma unroll
        for (int mi = 0; mi < 4; mi++) {
            #pragma unroll
            for (int j = 0; j < 4; j++) {
                int row = m0 + wr + mi*16 + fq*4 + j;
                if (row < M_TOK) {
                    int bq = row / N_;
                    int cc = row - bq*N_;
                    unsigned short* vrow = vbf + (size_t)row*768 + v0 + wc;
                    #pragma unroll
                    for (int ni = 0; ni < 4; ni++) {
                        unsigned short vb16 = bfr_(acc[mi][ni][j]);
                        int vcol = v0 + wc + ni*16 + fr;
                        vrow[ni*16 + fr] = vb16;
                        int hh = vcol >> 6, dd = vcol & 63;
                        vbfT[((size_t)(bq*NH_ + hh)*64 + dd)*224 + cc] = vb16;
                    }
                }
            }
        }
    }
}

// ---------------- proj+branch GEMM (K=896 bf16 MFMA, minimum-2-phase) + fused blend ----------------
__global__ __launch_bounds__(256) void gemm_proj(
    const unsigned short* __restrict__ A2, const unsigned short* __restrict__ W2,
    const float* __restrict__ bias,
    const float* __restrict__ x, const float* __restrict__ SC,
    float* __restrict__ out)
{
    __shared__ unsigned short At[2][128*32];
    __shared__ unsigned short Bt[2][128*32];
    const int nwg = gridDim.x;
    int q = nwg >> 3, rr = nwg & 7;
    int xcd = blockIdx.x & 7, idx = blockIdx.x >> 3;
    int s = (xcd < rr) ? xcd*(q+1) + idx : rr*(q+1) + (xcd - rr)*q + idx;
    const int n0 = (s % 6) * 128, m0 = (s / 6) * 128;
    const int tid = threadIdx.x;
    const int wave = tid >> 6, lane = tid & 63;
    const int wr = (wave >> 1)*64, wc = (wave & 1)*64;
    const int fr = lane & 15, fq = lane >> 4;
    const int xk = (fq ^ (fr & 3)) * 8;

    f32x4_ acc[4][4] = {};

    #define CLA_(r) ((m0 + (r) < M_TOK) ? (m0 + (r)) : (M_TOK-1))
    #define CLB_(r) (n0 + (r))
    STAGE_TILE2(At[0], A2, CLA_, 0, K2P_)
    STAGE_TILE2(Bt[0], W2, CLB_, 0, K2P_)
    BAR_VM0();
    for (int kt = 0; kt < NTP_; kt++) {
        const int cur = kt & 1;
        if (kt + 1 < NTP_) {
            STAGE_TILE2(At[cur^1], A2, CLA_, (kt+1)*32, K2P_)
            STAGE_TILE2(Bt[cur^1], W2, CLB_, (kt+1)*32, K2P_)
        }
        bf16x8_ a[4], bb[4];
        #pragma unroll
        for (int i = 0; i < 4; i++) {
            a[i]  = *(const bf16x8_*)&At[cur][(wr + i*16 + fr)*32 + xk];
            bb[i] = *(const bf16x8_*)&Bt[cur][(wc + i*16 + fr)*32 + xk];
        }
        __builtin_amdgcn_s_setprio(1);
        #pragma unroll
        for (int mi = 0; mi < 4; mi++)
            #pragma unroll
            for (int ni = 0; ni < 4; ni++)
                acc[mi][ni] = __builtin_amdgcn_mfma_f32_16x16x32_bf16(a[mi], bb[ni], acc[mi][ni], 0, 0, 0);
        __builtin_amdgcn_s_setprio(0);
        if (kt + 1 < NTP_) BAR_VM0();
    }
    #undef CLA_
    #undef CLB_

    const float w0 = SC[0], w12 = SC[1] + SC[2];
    float bv[4];
    #pragma unroll
    for (int ni = 0; ni < 4; ni++) bv[ni] = bias[n0 + wc + ni*16 + fr];
    #pragma unroll
    for (int mi = 0; mi < 4; mi++) {
        #pragma unroll
        for (int j = 0; j < 4; j++) {
            int row = m0 + wr + mi*16 + fq*4 + j;
            if (row < M_TOK) {
                int b = row / N_;
                int n = row - b*N_;
                float* orow = out + (size_t)row*768 + n0 + wc;
                if (n == 0) {
                    const float* xr = x + (size_t)row*768 + n0 + wc;
                    #pragma unroll
                    for (int ni = 0; ni < 4; ni++)
                        orow[ni*16 + fr] = acc[mi][ni][j] + w0*bv[ni] + w12*xr[ni*16 + fr];
                } else {
                    #pragma unroll
                    for (int ni = 0; ni < 4; ni++)
                        orow[ni*16 + fr] = acc[mi][ni][j] + (w0 + w12)*bv[ni];
                }
            }
        }
    }
}

// ---------------- fused flash attention v2 (bf16 MFMA, no staging, LDS P-transfer) ----------------
__global__ __launch_bounds__(256) void flash_attn(
    const unsigned short* __restrict__ qkbf,
    const unsigned short* __restrict__ vbfT,
    const float* __restrict__ v_b,
    unsigned short* __restrict__ msa2)
{
    __shared__ unsigned short Plds[4][4][16][24];
    const int bh = blockIdx.x;
    const int b = bh / NH_, h = bh % NH_;
    const int tid = threadIdx.x;
    const int wv = tid >> 6, lane = tid & 63;
    const int fr = lane & 15, fq = lane >> 4;

    const unsigned short* Kg = qkbf + (size_t)(b*N_)*1536 + 768 + h*64;
    const unsigned short* Vg = vbfT + (size_t)bh*(64*224);

    bf16x8_ qf[4][2];
    #pragma unroll
    for (int nf = 0; nf < 4; nf++) {
        int qr = wv*64 + nf*16 + fr; if (qr > N_-1) qr = N_-1;
        const unsigned short* Qg = qkbf + (size_t)(b*N_ + qr)*1536 + h*64;
        qf[nf][0] = *(const bf16x8_*)(Qg + fq*8);
        qf[nf][1] = *(const bf16x8_*)(Qg + 32 + fq*8);
    }

    f32x4_ o[4][4];
    #pragma unroll
    for (int i = 0; i < 4; i++)
        #pragma unroll
        for (int j2 = 0; j2 < 4; j2++) { o[i][j2][0]=0.f; o[i][j2][1]=0.f; o[i][j2][2]=0.f; o[i][j2][3]=0.f; }
    float m_[4] = {-1e30f,-1e30f,-1e30f,-1e30f};
    float l_[4] = {0.f,0.f,0.f,0.f};

    for (int t = 0; t < 14; t++) {
        int kr = t*16 + fr; if (kr > N_-1) kr = N_-1;
        const unsigned short* krp = Kg + (size_t)kr*1536;
        bf16x8_ kf0 = *(const bf16x8_*)(krp + fq*8);
        bf16x8_ kf1 = *(const bf16x8_*)(krp + 32 + fq*8);
        f32x4_ st[4];
        __builtin_amdgcn_s_setprio(1);
        #pragma unroll
        for (int nf = 0; nf < 4; nf++) {
            f32x4_ z = {0.f,0.f,0.f,0.f};
            z = __builtin_amdgcn_mfma_f32_16x16x32_bf16(kf0, qf[nf][0], z, 0,0,0);
            z = __builtin_amdgcn_mfma_f32_16x16x32_bf16(kf1, qf[nf][1], z, 0,0,0);
            st[nf] = z;
        }
        __builtin_amdgcn_s_setprio(0);
        const int cbase = t*16 + fq*4;
        #pragma unroll
        for (int nf = 0; nf < 4; nf++) {
            #pragma unroll
            for (int jj = 0; jj < 4; jj++)
                st[nf][jj] = (cbase + jj < N_) ? st[nf][jj]*SCALE_ : -1e30f;
            float tm = fmaxf(fmaxf(st[nf][0],st[nf][1]), fmaxf(st[nf][2],st[nf][3]));
            tm = fmaxf(tm, __shfl_xor(tm, 16));
            tm = fmaxf(tm, __shfl_xor(tm, 32));
            if (__any(tm > m_[nf] + 8.f)) {
                float mn = fmaxf(m_[nf], tm);
                float sc = __expf(m_[nf] - mn);
                l_[nf] *= sc;
                m_[nf] = mn;
                #pragma unroll
                for (int df = 0; df < 4; df++) {
                    o[df][nf][0]*=sc; o[df][nf][1]*=sc; o[df][nf][2]*=sc; o[df][nf][3]*=sc;
                }
            }
            float mn = m_[nf];
            float e0 = __expf(st[nf][0] - mn);
            float e1 = __expf(st[nf][1] - mn);
            float e2 = __expf(st[nf][2] - mn);
            float e3 = __expf(st[nf][3] - mn);
            float ps = e0 + e1 + e2 + e3;
            ps += __shfl_xor(ps, 16);
            ps += __shfl_xor(ps, 32);
            l_[nf] += ps;
            unsigned lo = (unsigned)bfr_(e0) | ((unsigned)bfr_(e1) << 16);
            unsigned hi = (unsigned)bfr_(e2) | ((unsigned)bfr_(e3) << 16);
            *(uint2*)&Plds[wv][nf][fr][fq*4] = make_uint2(lo, hi);
        }
        asm volatile("s_waitcnt lgkmcnt(0)" ::: "memory");
        __builtin_amdgcn_sched_barrier(0);
        bf16x8_ pa[4];
        #pragma unroll
        for (int nf = 0; nf < 4; nf++) {
            if (fq < 2) pa[nf] = *(const bf16x8_*)&Plds[wv][nf][fr][fq*8];
            else { bf16x8_ z2 = {0,0,0,0,0,0,0,0}; pa[nf] = z2; }
        }
        __builtin_amdgcn_s_setprio(1);
        #pragma unroll
        for (int df = 0; df < 4; df++) {
            int d = df*16 + fr;
            int ko = t*16 + fq*8; if (ko > 216) ko = 216;
            bf16x8_ vf = *(const bf16x8_*)(Vg + (size_t)d*224 + ko);
            #pragma unroll
            for (int nf = 0; nf < 4; nf++)
                o[df][nf] = __builtin_amdgcn_mfma_f32_16x16x32_bf16(vf, pa[nf], o[df][nf], 0,0,0);
        }
        __builtin_amdgcn_s_setprio(0);
    }
    #pragma unroll
    for (int nf = 0; nf < 4; nf++) {
        int qr = wv*64 + nf*16 + fr;
        if (qr >= N_) continue;
        float inv = 1.f / l_[nf];
        unsigned short* orow = msa2 + (size_t)(b*N_ + qr)*K2P_ + h*64;
        #pragma unroll
        for (int df = 0; df < 4; df++) {
            const float4 vb4 = *(const float4*)&v_b[h*64 + df*16 + fq*4];
            unsigned u0 = (unsigned)bfr_(o[df][nf][0]*inv + vb4.x)
                        | ((unsigned)bfr_(o[df][nf][1]*inv + vb4.y) << 16);
            unsigned u1 = (unsigned)bfr_(o[df][nf][2]*inv + vb4.z)
                        | ((unsigned)bfr_(o[df][nf][3]*inv + vb4.w) << 16);
            uint2 w; w.x = u0; w.y = u1;
            *(uint2*)(orow + df*16 + fq*4) = w;
        }
    }
}

// ---------------- new_v (bf16 in, bf16 out) ----------------
__global__ __launch_bounds__(256) void newv_kernel(
    const unsigned short* __restrict__ vbf, const float* __restrict__ SC,
    unsigned short* __restrict__ newvb)
{
    int idx = blockIdx.x*256 + threadIdx.x;
    if (idx >= M_PATCH*64) return;
    int d = idx & 63; int bp = idx >> 6;
    int p = bp % NP_, b = bp / NP_;
    const unsigned short* src = vbf + (size_t)(b*N_ + 1 + p)*768 + d;
    float vh[12];
    #pragma unroll
    for (int h = 0; h < 12; h++) vh[h] = bf2f_(src[h*64]);
    #pragma unroll
    for (int k = 0; k < 9; k++) {
        float s = 0.f;
        #pragma unroll
        for (int h = 0; h < 12; h++) s += vh[h]*SC[HP_OFF + h*9 + k];
        newvb[((size_t)bp*9 + k)*64 + d] = bfr_(s);
    }
}

// ---------------- fused c1pre + c3pre + BN partial stats -> bf16 c13 ----------------
__global__ __launch_bounds__(256) void fuse13_kernel(
    const unsigned short* __restrict__ newvb, const float* __restrict__ SC,
    unsigned short* __restrict__ c13bf, float* __restrict__ part)
{
    __shared__ float sd1[256], sq1[256], sd3[256], sq3[256];
    int tid = threadIdx.x;
    float s1 = 0.f, q1 = 0.f, s3 = 0.f, q3 = 0.f;
    for (int i = blockIdx.x*256 + tid; i < M_PATCH*64; i += 65536) {
        int d = i & 63; int bij = i >> 6;
        int j = bij % 14; int bi = bij / 14; int irow = bi % 14; int b = bi / 14;
        float c1v = bf2f_(newvb[((size_t)bij*9 + 4)*64 + d]) + SC[NVB_OFF + d*9 + 4];
        float c3v = SC[SVB_OFF + d];
        #pragma unroll
        for (int p = 0; p < 9; p++) {
            int h1 = p % 3, h2 = p / 3;
            int y = irow + h1 - 1, xx = j + h2 - 1;
            if (y >= 0 && y < 14 && xx >= 0 && xx < 14)
                c3v += bf2f_(newvb[(((size_t)b*NP_ + y*14 + xx)*9 + p)*64 + d]);
        }
        c13bf[(size_t)bij*128 + d]      = bfr_(c1v);
        c13bf[(size_t)bij*128 + 64 + d] = bfr_(c3v);
        s1 += c1v; q1 += c1v*c1v; s3 += c3v; q3 += c3v*c3v;
    }
    sd1[tid] = s1; sq1[tid] = q1; sd3[tid] = s3; sq3[tid] = q3;
    __syncthreads();
    if (tid < 64) {
        part[blockIdx.x*256 + tid]       = sd1[tid]+sd1[tid+64]+sd1[tid+128]+sd1[tid+192];
        part[blockIdx.x*256 + 64 + tid]  = sq1[tid]+sq1[tid+64]+sq1[tid+128]+sq1[tid+192];
        part[blockIdx.x*256 + 128 + tid] = sd3[tid]+sd3[tid+64]+sd3[tid+128]+sd3[tid+192];
        part[blockIdx.x*256 + 192 + tid] = sq3[tid]+sq3[tid+64]+sq3[tid+128]+sq3[tid+192];
    }
}

// ---------------- reduce both BN stats -> scale/offset pairs ----------------
__global__ void bnreduce2_kernel(const float* __restrict__ part,
                                 const float* __restrict__ g1, const float* __restrict__ b1,
                                 const float* __restrict__ g3, const float* __restrict__ b3,
                                 float* __restrict__ stats)
{
    __shared__ float red[256];
    int t = threadIdx.x;  // 256
    float s = 0.f;
    for (int i = 0; i < 256; i++) s += part[i*256 + t];
    red[t] = s;
    __syncthreads();
    const float invN = 1.0f/12544.0f;
    if (t < 64) {
        float mean = red[t]*invN;
        float var  = red[64+t]*invN - mean*mean;
        float sc = rsqrtf(var + BN_EPS_) * g1[t];
        stats[t]      = sc;
        stats[64+t]   = b1[t] - mean*sc;
    } else if (t < 128) {
        int d = t - 64;
        float mean = red[128+d]*invN;
        float var  = red[192+d]*invN - mean*mean;
        float sc = rsqrtf(var + BN_EPS_) * g3[d];
        stats[128+d]  = sc;
        stats[192+d]  = b3[d] - mean*sc;
    }
}

// ---------------- BN apply + relu -> act13 (bf16, M_TOK layout, cls rows = 0) ----------------
__global__ __launch_bounds__(256) void bnapply13_kernel(
    const unsigned short* __restrict__ c13bf, const float* __restrict__ stats,
    unsigned short* __restrict__ msa2)
{
    int idx = blockIdx.x*256 + threadIdx.x;
    if (idx >= M_TOK*128) return;
    int k = idx & 127; int row = idx >> 7;
    int b = row / N_; int n = row - b*N_;
    float val = 0.f;
    if (n > 0) {
        float v = bf2f_(c13bf[(size_t)(b*NP_ + n - 1)*128 + k]);
        float sc, off;
        if (k < 64) { sc = stats[k]; off = stats[64+k]; }
        else        { sc = stats[64+k]; off = stats[128+k]; }
        val = fmaxf(v*sc + off, 0.f);
    }
    msa2[(size_t)row*K2P_ + 768 + k] = bfr_(val);
}

// ---------------- combined proj weights: Wp[c][0:768]=w0*proj_w, [768:896]=Wc ----------------
__global__ __launch_bounds__(256) void w13_kernel(
    const float* __restrict__ proj_w, const float* __restrict__ SC,
    unsigned short* __restrict__ Wp)
{
    int idx = blockIdx.x*256 + threadIdx.x;
    if (idx >= 768*K2P_) return;
    int k = idx % K2P_, c = idx / K2P_;
    float s;
    if (k < 768) {
        s = SC[0] * proj_w[(size_t)c*768 + k];
    } else {
        int d2 = k - 768;
        s = 0.f;
        if (d2 < 64) {
            #pragma unroll
            for (int h = 0; h < 12; h++)
                s += proj_w[(size_t)c*768 + h*64 + d2] * SC[HP_OFF + h*9 + 4];
            s *= SC[2];   // w2 * W1
        } else {
            int dd = d2 - 64;
            #pragma unroll
            for (int h = 0; h < 12; h++)
                s += proj_w[(size_t)c*768 + h*64 + dd] * SC[HPROW_OFF + h];
            s *= SC[1];   // w1 * W3
        }
    }
    Wp[(size_t)c*K2P_ + k] = bfr_(s);
}

// ---------------- launch ----------------
extern "C" void kernel_launch(void* const* d_in, const int* in_sizes, int n_in,
                              void* d_out, int out_size, void* d_ws, size_t ws_size,
                              hipStream_t stream)
{
    const float* x        = (const float*)d_in[0];
    const float* uniforms = (const float*)d_in[1];
    const float* qk_w     = (const float*)d_in[2];
    const float* qk_b     = (const float*)d_in[3];
    const float* v_w      = (const float*)d_in[4];
    const float* v_b      = (const float*)d_in[5];
    const float* proj_w   = (const float*)d_in[6];
    const float* proj_b   = (const float*)d_in[7];
    const float* bn1_g    = (const float*)d_in[8];
    const float* bn1_b    = (const float*)d_in[9];
    const float* bn3_g    = (const float*)d_in[10];
    const float* bn3_b    = (const float*)d_in[11];
    const float* kth      = (const float*)d_in[12];
    const float* head_probs = (const float*)d_in[13];
    float* out = (float*)d_out;

    // ws regions; every alias written-in-full (or written-then-read) in order each call
    float* ws = (float*)d_ws;
    float* R1 = ws;                     // 19,365,888 floats
    float* R2 = ws + 19365888;          //  9,682,944 floats
    float* R3 = ws + 29048832;          //  9,682,944 floats
    float* SC = ws + 38731776;          //    132,096 floats
    unsigned short* qkbf = (unsigned short*)R1;
    unsigned short* vbfT = (unsigned short*)R1 + 19365888;
    unsigned short* newvb = (unsigned short*)R1;
    unsigned short* vbf = (unsigned short*)R2;
    unsigned short* c13bf = (unsigned short*)R2;
    unsigned int*   x2   = (unsigned int*)R3;
    unsigned short* msa2 = (unsigned short*)R3;
    float* part = R3 + 6000000;
    unsigned short* Wp = (unsigned short*)(R3 + 6200000);
    unsigned int* W2a = (unsigned int*)out;
    unsigned int* W2b = (unsigned int*)out + 589824;
    float* stats = SC + STATS_OFF;

    prep_kernel<<<1, 256, 0, stream>>>(uniforms, kth, head_probs, v_b, SC, out + OUT_MAIN);

    conv_all<<<5592, 256, 0, stream>>>(x, qk_w, v_w, x2, W2a, W2b);

    gemm_qkv<<<1782, 256, 0, stream>>>((const unsigned short*)x2,
                                       (const unsigned short*)W2a, qk_b,
                                       qkbf, vbf, (unsigned short*)vbfT);

    flash_attn<<<768, 256, 0, stream>>>(qkbf, (const unsigned short*)vbfT, v_b, msa2);

    // conv branch chain
    newv_kernel<<<3136, 256, 0, stream>>>(vbf, SC, newvb);
    fuse13_kernel<<<256, 256, 0, stream>>>(newvb, SC, c13bf, part);
    bnreduce2_kernel<<<1, 256, 0, stream>>>(part, bn1_g, bn1_b, bn3_g, bn3_b, stats);
    bnapply13_kernel<<<6304, 256, 0, stream>>>(c13bf, stats, msa2);
    w13_kernel<<<2688, 256, 0, stream>>>(proj_w, SC, Wp);

    // proj + branch + blend -> out (K=896)
    gemm_proj<<<594, 256, 0, stream>>>(msa2, Wp, proj_b, x, SC, out);
}

// Round 16
// 261.012 us; speedup vs baseline: 1.0906x; 1.0906x over previous
//
#include <hip/hip_runtime.h>
#include <cstdint>
#include <cstddef>

// ---------------- problem constants ----------------
#define B_    64
#define N_    197
#define DIM_  768
#define NH_   12
#define HD_   64
#define NP_   196
#define SCALE_ 0.125f
#define EPS_   1.1920929e-07f
#define BN_EPS_ 1e-5f
#define ALPHA_ 0.01f

#define M_TOK   (B_*N_)        // 12608
#define M_PATCH (B_*NP_)       // 12544
#define OUT_MAIN (M_TOK*DIM_)  // 9682944

#define K2_  768               // qkv GEMM K (bf16)
#define NT_  24                // K2_/32
#define K2P_ 896               // proj GEMM K = 768 (msa) + 128 (act13)
#define NTP_ 28                // K2P_/32

// scalar workspace layout (float offsets within SC)
#define W_OFF     0
#define HP_OFF    16
#define HPROW_OFF 128
#define NVB_OFF   144
#define SVB_OFF   720
#define STATS_OFF 784          // 256 floats: sc1,off1,sc3,off3
#define SC_FLOATS 132096

typedef short bf16x8_ __attribute__((ext_vector_type(8)));
typedef float f32x4_  __attribute__((ext_vector_type(4)));

// ---------------- prep ----------------
__global__ void prep_kernel(const float* __restrict__ uniforms, const float* __restrict__ kth,
                            const float* __restrict__ head_probs, const float* __restrict__ v_b,
                            float* __restrict__ SC, float* __restrict__ out_tail)
{
    int t = threadIdx.x;
    if (t == 0) {
        float ind[3];
        for (int i = 0; i < 3; i++) {
            float s = 1.f/(1.f + expf(-kth[i]));
            float p = fminf(fmaxf(s, EPS_), 1.f - EPS_);
            float u = fminf(fmaxf(uniforms[i], EPS_), 1.f - EPS_);
            float logit = logf(u) - log1pf(-u) + logf(p) - log1pf(-p);
            ind[i] = (logit > 0.f) ? 1.f : 0.f;
        }
        SC[W_OFF+0] = ind[2];
        SC[W_OFF+1] = ind[1]*(1.f-ind[2]);
        SC[W_OFF+2] = ind[0]*(1.f-ind[1])*(1.f-ind[2]);
        float kprod = 1.f;
        for (int i = 0; i < 3; i++) {
            float ktv = 1.f/(1.f + expf(-kth[i]));
            kprod *= (ktv > 0.5f) ? 1.f : 0.f;
            out_tail[i]   = kprod;
            out_tail[3+i] = ktv;
        }
    }
    if (t < 9) {
        float mx = -1e30f;
        for (int h = 0; h < 12; h++) mx = fmaxf(mx, head_probs[h*9+t]);
        float e[12]; float s = 0.f;
        for (int h = 0; h < 12; h++) { e[h] = expf((head_probs[h*9+t]-mx)/ALPHA_); s += e[h]; }
        for (int h = 0; h < 12; h++) SC[HP_OFF + h*9 + t] = e[h]/s;
    }
    __syncthreads();
    if (t < 12) {
        float s = 0.f;
        for (int k = 0; k < 9; k++) s += SC[HP_OFF + t*9 + k];
        SC[HPROW_OFF + t] = s;
    }
    if (t < 64) {
        float sv = 0.f;
        for (int k = 0; k < 9; k++) {
            float s = 0.f;
            for (int h = 0; h < 12; h++) s += v_b[h*64+t]*SC[HP_OFF + h*9 + k];
            SC[NVB_OFF + t*9 + k] = s;
            sv += s;
        }
        SC[SVB_OFF + t] = sv;
    }
}

// ---------------- fp32 -> bf16 (RNE) ----------------
__device__ __forceinline__ unsigned short bfr_(float f) {
    unsigned u = __float_as_uint(f);
    return (unsigned short)((u + 0x7FFFu + ((u >> 16) & 1u)) >> 16);
}
__device__ __forceinline__ float bf2f_(unsigned short u) {
    return __uint_as_float((unsigned)u << 16);
}

// single fused conversion for x, qk_w, v_w
__global__ __launch_bounds__(256) void conv_all(
    const float* __restrict__ x, const float* __restrict__ qkw, const float* __restrict__ vw,
    unsigned int* __restrict__ x2, unsigned int* __restrict__ W2a, unsigned int* __restrict__ W2b)
{
    int i = blockIdx.x*256 + threadIdx.x;
    const float* src; unsigned int* dst; int off;
    if (i < 1210368)      { src = x;   dst = x2;  off = i; }
    else if (i < 1357824) { src = qkw; dst = W2a; off = i - 1210368; }
    else if (i < 1431552) { src = vw;  dst = W2b; off = i - 1357824; }
    else return;
    float4 a = ((const float4*)src)[2*off];
    float4 b = ((const float4*)src)[2*off+1];
    unsigned r0 = (unsigned)bfr_(a.x) | ((unsigned)bfr_(a.y) << 16);
    unsigned r1 = (unsigned)bfr_(a.z) | ((unsigned)bfr_(a.w) << 16);
    unsigned r2 = (unsigned)bfr_(b.x) | ((unsigned)bfr_(b.y) << 16);
    unsigned r3 = (unsigned)bfr_(b.z) | ((unsigned)bfr_(b.w) << 16);
    ((uint4*)dst)[off] = make_uint4(r0, r1, r2, r3);
}

// ---- global_load_lds staging (linear [128][32] ushorts; per-lane XOR src, XOR read) ----
#define STAGE_TILE2(LDSPTR, GBASE, ROWCLAMP, KOFF, STRIDE)                               \
    {                                                                                    \
        _Pragma("unroll")                                                                \
        for (int i_ = 0; i_ < 2; i_++) {                                                 \
            int r_ = wave*32 + i_*16 + (lane >> 2);                                      \
            int gr_ = ROWCLAMP(r_);                                                      \
            const unsigned short* gp_ = (GBASE) + (size_t)gr_*(STRIDE) + (KOFF)          \
                                        + (((lane & 3) ^ (r_ & 3)) * 8);                 \
            __builtin_amdgcn_global_load_lds(                                            \
                (const __attribute__((address_space(1))) unsigned int*)gp_,              \
                (__attribute__((address_space(3))) unsigned int*)&(LDSPTR)[(wave*32 + i_*16)*32], \
                16, 0, 0);                                                               \
        }                                                                                \
    }

// read-complete fence: ds_reads drained, raw barrier (NO vmcnt drain)
#define BAR_LGKM() asm volatile("s_waitcnt lgkmcnt(0)\n\ts_barrier" ::: "memory")
// counted fence: wait until only the 4 newest per-wave loads remain in flight
#define BAR_VM4()  asm volatile("s_waitcnt vmcnt(4)\n\ts_barrier" ::: "memory")
#define BAR_VM0()  asm volatile("s_waitcnt vmcnt(0)\n\ts_barrier" ::: "memory")

// ---------------- merged qk+v GEMM (bf16 MFMA, 2-deep counted-vmcnt pipeline) ----------------
__global__ __launch_bounds__(256) void gemm_qkv(
    const unsigned short* __restrict__ A2, const unsigned short* __restrict__ W2,
    const float* __restrict__ qk_b,
    unsigned short* __restrict__ qkbf, unsigned short* __restrict__ vbf,
    unsigned short* __restrict__ vbfT)
{
    __shared__ unsigned short At[2][128*32];
    __shared__ unsigned short Bt[2][128*32];
    const int nwg = 1782;
    int q = nwg >> 3, rr = nwg & 7;
    int xcd = blockIdx.x & 7, idx = blockIdx.x >> 3;
    int s = (xcd < rr) ? xcd*(q+1) + idx : rr*(q+1) + (xcd - rr)*q + idx;
    const int n0 = (s % 18) * 128, m0 = (s / 18) * 128;
    const int tid = threadIdx.x;
    const int wave = tid >> 6, lane = tid & 63;
    const int wr = (wave >> 1)*64, wc = (wave & 1)*64;
    const int fr = lane & 15, fq = lane >> 4;
    const int xk = (fq ^ (fr & 3)) * 8;

    f32x4_ acc[4][4] = {};

    #define CLA_(r) ((m0 + (r) < M_TOK) ? (m0 + (r)) : (M_TOK-1))
    #define CLB_(r) (n0 + (r))
    STAGE_TILE2(At[0], A2, CLA_, 0, K2_)
    STAGE_TILE2(Bt[0], W2, CLB_, 0, K2_)
    STAGE_TILE2(At[1], A2, CLA_, 32, K2_)
    STAGE_TILE2(Bt[1], W2, CLB_, 32, K2_)
    BAR_VM4();
    for (int kt = 0; kt < NT_; kt++) {
        const int cur = kt & 1;
        bf16x8_ a[4], bb[4];
        #pragma unroll
        for (int i = 0; i < 4; i++) {
            a[i]  = *(const bf16x8_*)&At[cur][(wr + i*16 + fr)*32 + xk];
            bb[i] = *(const bf16x8_*)&Bt[cur][(wc + i*16 + fr)*32 + xk];
        }
        #pragma unroll
        for (int mi = 0; mi < 4; mi++)
            #pragma unroll
            for (int ni = 0; ni < 4; ni++)
                acc[mi][ni] = __builtin_amdgcn_mfma_f32_16x16x32_bf16(a[mi], bb[ni], acc[mi][ni], 0, 0, 0);
        BAR_LGKM();
        if (kt + 2 < NT_) {
            STAGE_TILE2(At[cur], A2, CLA_, (kt+2)*32, K2_)
            STAGE_TILE2(Bt[cur], W2, CLB_, (kt+2)*32, K2_)
            BAR_VM4();
        } else if (kt + 1 < NT_) {
            BAR_VM0();
        }
    }
    #undef CLA_
    #undef CLB_

    if (n0 < 1536) {
        float bv[4];
        #pragma unroll
        for (int ni = 0; ni < 4; ni++) bv[ni] = qk_b[n0 + wc + ni*16 + fr];
        #pragma unroll
        for (int mi = 0; mi < 4; mi++) {
            #pragma unroll
            for (int j = 0; j < 4; j++) {
                int row = m0 + wr + mi*16 + fq*4 + j;
                if (row < M_TOK) {
                    unsigned short* crow = qkbf + (size_t)row*1536 + n0 + wc;
                    #pragma unroll
                    for (int ni = 0; ni < 4; ni++)
                        crow[ni*16 + fr] = bfr_(acc[mi][ni][j] + bv[ni]);
                }
            }
        }
    } else {
        const int v0 = n0 - 1536;
        #pragma unroll
        for (int mi = 0; mi < 4; mi++) {
            #pragma unroll
            for (int j = 0; j < 4; j++) {
                int row = m0 + wr + mi*16 + fq*4 + j;
                if (row < M_TOK) {
                    int bq = row / N_;
                    int cc = row - bq*N_;
                    unsigned short* vrow = vbf + (size_t)row*768 + v0 + wc;
                    #pragma unroll
                    for (int ni = 0; ni < 4; ni++) {
                        unsigned short vb16 = bfr_(acc[mi][ni][j]);
                        int vcol = v0 + wc + ni*16 + fr;
                        vrow[ni*16 + fr] = vb16;
                        int hh = vcol >> 6, dd = vcol & 63;
                        vbfT[((size_t)(bq*NH_ + hh)*64 + dd)*224 + cc] = vb16;
                    }
                }
            }
        }
    }
}

// ---------------- proj+branch GEMM (K=896 bf16 MFMA, 2-deep pipeline) + fused blend ----------------
__global__ __launch_bounds__(256) void gemm_proj(
    const unsigned short* __restrict__ A2, const unsigned short* __restrict__ W2,
    const float* __restrict__ bias,
    const float* __restrict__ x, const float* __restrict__ SC,
    float* __restrict__ out)
{
    __shared__ unsigned short At[2][128*32];
    __shared__ unsigned short Bt[2][128*32];
    const int nwg = gridDim.x;
    int q = nwg >> 3, rr = nwg & 7;
    int xcd = blockIdx.x & 7, idx = blockIdx.x >> 3;
    int s = (xcd < rr) ? xcd*(q+1) + idx : rr*(q+1) + (xcd - rr)*q + idx;
    const int n0 = (s % 6) * 128, m0 = (s / 6) * 128;
    const int tid = threadIdx.x;
    const int wave = tid >> 6, lane = tid & 63;
    const int wr = (wave >> 1)*64, wc = (wave & 1)*64;
    const int fr = lane & 15, fq = lane >> 4;
    const int xk = (fq ^ (fr & 3)) * 8;

    f32x4_ acc[4][4] = {};

    #define CLA_(r) ((m0 + (r) < M_TOK) ? (m0 + (r)) : (M_TOK-1))
    #define CLB_(r) (n0 + (r))
    STAGE_TILE2(At[0], A2, CLA_, 0, K2P_)
    STAGE_TILE2(Bt[0], W2, CLB_, 0, K2P_)
    STAGE_TILE2(At[1], A2, CLA_, 32, K2P_)
    STAGE_TILE2(Bt[1], W2, CLB_, 32, K2P_)
    BAR_VM4();
    for (int kt = 0; kt < NTP_; kt++) {
        const int cur = kt & 1;
        bf16x8_ a[4], bb[4];
        #pragma unroll
        for (int i = 0; i < 4; i++) {
            a[i]  = *(const bf16x8_*)&At[cur][(wr + i*16 + fr)*32 + xk];
            bb[i] = *(const bf16x8_*)&Bt[cur][(wc + i*16 + fr)*32 + xk];
        }
        #pragma unroll
        for (int mi = 0; mi < 4; mi++)
            #pragma unroll
            for (int ni = 0; ni < 4; ni++)
                acc[mi][ni] = __builtin_amdgcn_mfma_f32_16x16x32_bf16(a[mi], bb[ni], acc[mi][ni], 0, 0, 0);
        BAR_LGKM();
        if (kt + 2 < NTP_) {
            STAGE_TILE2(At[cur], A2, CLA_, (kt+2)*32, K2P_)
            STAGE_TILE2(Bt[cur], W2, CLB_, (kt+2)*32, K2P_)
            BAR_VM4();
        } else if (kt + 1 < NTP_) {
            BAR_VM0();
        }
    }
    #undef CLA_
    #undef CLB_

    const float w0 = SC[0], w12 = SC[1] + SC[2];
    float bv[4];
    #pragma unroll
    for (int ni = 0; ni < 4; ni++) bv[ni] = bias[n0 + wc + ni*16 + fr];
    #pragma unroll
    for (int mi = 0; mi < 4; mi++) {
        #pragma unroll
        for (int j = 0; j < 4; j++) {
            int row = m0 + wr + mi*16 + fq*4 + j;
            if (row < M_TOK) {
                int b = row / N_;
                int n = row - b*N_;
                float* orow = out + (size_t)row*768 + n0 + wc;
                if (n == 0) {
                    const float* xr = x + (size_t)row*768 + n0 + wc;
                    #pragma unroll
                    for (int ni = 0; ni < 4; ni++)
                        orow[ni*16 + fr] = acc[mi][ni][j] + w0*bv[ni] + w12*xr[ni*16 + fr];
                } else {
                    #pragma unroll
                    for (int ni = 0; ni < 4; ni++)
                        orow[ni*16 + fr] = acc[mi][ni][j] + (w0 + w12)*bv[ni];
                }
            }
        }
    }
}

// ---------------- fused flash attention v2 (bf16 MFMA, no staging, LDS P-transfer) ----------------
__global__ __launch_bounds__(256) void flash_attn(
    const unsigned short* __restrict__ qkbf,
    const unsigned short* __restrict__ vbfT,
    const float* __restrict__ v_b,
    unsigned short* __restrict__ msa2)
{
    __shared__ unsigned short Plds[4][4][16][24];
    const int bh = blockIdx.x;
    const int b = bh / NH_, h = bh % NH_;
    const int tid = threadIdx.x;
    const int wv = tid >> 6, lane = tid & 63;
    const int fr = lane & 15, fq = lane >> 4;

    const unsigned short* Kg = qkbf + (size_t)(b*N_)*1536 + 768 + h*64;
    const unsigned short* Vg = vbfT + (size_t)bh*(64*224);

    bf16x8_ qf[4][2];
    #pragma unroll
    for (int nf = 0; nf < 4; nf++) {
        int qr = wv*64 + nf*16 + fr; if (qr > N_-1) qr = N_-1;
        const unsigned short* Qg = qkbf + (size_t)(b*N_ + qr)*1536 + h*64;
        qf[nf][0] = *(const bf16x8_*)(Qg + fq*8);
        qf[nf][1] = *(const bf16x8_*)(Qg + 32 + fq*8);
    }

    f32x4_ o[4][4];
    #pragma unroll
    for (int i = 0; i < 4; i++)
        #pragma unroll
        for (int j2 = 0; j2 < 4; j2++) { o[i][j2][0]=0.f; o[i][j2][1]=0.f; o[i][j2][2]=0.f; o[i][j2][3]=0.f; }
    float m_[4] = {-1e30f,-1e30f,-1e30f,-1e30f};
    float l_[4] = {0.f,0.f,0.f,0.f};

    for (int t = 0; t < 14; t++) {
        int kr = t*16 + fr; if (kr > N_-1) kr = N_-1;
        const unsigned short* krp = Kg + (size_t)kr*1536;
        bf16x8_ kf0 = *(const bf16x8_*)(krp + fq*8);
        bf16x8_ kf1 = *(const bf16x8_*)(krp + 32 + fq*8);
        f32x4_ st[4];
        __builtin_amdgcn_s_setprio(1);
        #pragma unroll
        for (int nf = 0; nf < 4; nf++) {
            f32x4_ z = {0.f,0.f,0.f,0.f};
            z = __builtin_amdgcn_mfma_f32_16x16x32_bf16(kf0, qf[nf][0], z, 0,0,0);
            z = __builtin_amdgcn_mfma_f32_16x16x32_bf16(kf1, qf[nf][1], z, 0,0,0);
            st[nf] = z;
        }
        __builtin_amdgcn_s_setprio(0);
        const int cbase = t*16 + fq*4;
        #pragma unroll
        for (int nf = 0; nf < 4; nf++) {
            #pragma unroll
            for (int jj = 0; jj < 4; jj++)
                st[nf][jj] = (cbase + jj < N_) ? st[nf][jj]*SCALE_ : -1e30f;
            float tm = fmaxf(fmaxf(st[nf][0],st[nf][1]), fmaxf(st[nf][2],st[nf][3]));
            tm = fmaxf(tm, __shfl_xor(tm, 16));
            tm = fmaxf(tm, __shfl_xor(tm, 32));
            if (__any(tm > m_[nf] + 8.f)) {
                float mn = fmaxf(m_[nf], tm);
                float sc = __expf(m_[nf] - mn);
                l_[nf] *= sc;
                m_[nf] = mn;
                #pragma unroll
                for (int df = 0; df < 4; df++) {
                    o[df][nf][0]*=sc; o[df][nf][1]*=sc; o[df][nf][2]*=sc; o[df][nf][3]*=sc;
                }
            }
            float mn = m_[nf];
            float e0 = __expf(st[nf][0] - mn);
            float e1 = __expf(st[nf][1] - mn);
            float e2 = __expf(st[nf][2] - mn);
            float e3 = __expf(st[nf][3] - mn);
            float ps = e0 + e1 + e2 + e3;
            ps += __shfl_xor(ps, 16);
            ps += __shfl_xor(ps, 32);
            l_[nf] += ps;
            unsigned lo = (unsigned)bfr_(e0) | ((unsigned)bfr_(e1) << 16);
            unsigned hi = (unsigned)bfr_(e2) | ((unsigned)bfr_(e3) << 16);
            *(uint2*)&Plds[wv][nf][fr][fq*4] = make_uint2(lo, hi);
        }
        asm volatile("s_waitcnt lgkmcnt(0)" ::: "memory");
        __builtin_amdgcn_sched_barrier(0);
        bf16x8_ pa[4];
        #pragma unroll
        for (int nf = 0; nf < 4; nf++) {
            if (fq < 2) pa[nf] = *(const bf16x8_*)&Plds[wv][nf][fr][fq*8];
            else { bf16x8_ z2 = {0,0,0,0,0,0,0,0}; pa[nf] = z2; }
        }
        __builtin_amdgcn_s_setprio(1);
        #pragma unroll
        for (int df = 0; df < 4; df++) {
            int d = df*16 + fr;
            int ko = t*16 + fq*8; if (ko > 216) ko = 216;
            bf16x8_ vf = *(const bf16x8_*)(Vg + (size_t)d*224 + ko);
            #pragma unroll
            for (int nf = 0; nf < 4; nf++)
                o[df][nf] = __builtin_amdgcn_mfma_f32_16x16x32_bf16(vf, pa[nf], o[df][nf], 0,0,0);
        }
        __builtin_amdgcn_s_setprio(0);
    }
    #pragma unroll
    for (int nf = 0; nf < 4; nf++) {
        int qr = wv*64 + nf*16 + fr;
        if (qr >= N_) continue;
        float inv = 1.f / l_[nf];
        unsigned short* orow = msa2 + (size_t)(b*N_ + qr)*K2P_ + h*64;
        #pragma unroll
        for (int df = 0; df < 4; df++) {
            const float4 vb4 = *(const float4*)&v_b[h*64 + df*16 + fq*4];
            unsigned u0 = (unsigned)bfr_(o[df][nf][0]*inv + vb4.x)
                        | ((unsigned)bfr_(o[df][nf][1]*inv + vb4.y) << 16);
            unsigned u1 = (unsigned)bfr_(o[df][nf][2]*inv + vb4.z)
                        | ((unsigned)bfr_(o[df][nf][3]*inv + vb4.w) << 16);
            uint2 w; w.x = u0; w.y = u1;
            *(uint2*)(orow + df*16 + fq*4) = w;
        }
    }
}

// ---------------- new_v (bf16 in, bf16 out) ----------------
__global__ __launch_bounds__(256) void newv_kernel(
    const unsigned short* __restrict__ vbf, const float* __restrict__ SC,
    unsigned short* __restrict__ newvb)
{
    int idx = blockIdx.x*256 + threadIdx.x;
    if (idx >= M_PATCH*64) return;
    int d = idx & 63; int bp = idx >> 6;
    int p = bp % NP_, b = bp / NP_;
    const unsigned short* src = vbf + (size_t)(b*N_ + 1 + p)*768 + d;
    float vh[12];
    #pragma unroll
    for (int h = 0; h < 12; h++) vh[h] = bf2f_(src[h*64]);
    #pragma unroll
    for (int k = 0; k < 9; k++) {
        float s = 0.f;
        #pragma unroll
        for (int h = 0; h < 12; h++) s += vh[h]*SC[HP_OFF + h*9 + k];
        newvb[((size_t)bp*9 + k)*64 + d] = bfr_(s);
    }
}

// ---------------- fused c1pre + c3pre + BN partial stats -> bf16 c13 ----------------
__global__ __launch_bounds__(256) void fuse13_kernel(
    const unsigned short* __restrict__ newvb, const float* __restrict__ SC,
    unsigned short* __restrict__ c13bf, float* __restrict__ part)
{
    __shared__ float sd1[256], sq1[256], sd3[256], sq3[256];
    int tid = threadIdx.x;
    float s1 = 0.f, q1 = 0.f, s3 = 0.f, q3 = 0.f;
    for (int i = blockIdx.x*256 + tid; i < M_PATCH*64; i += 65536) {
        int d = i & 63; int bij = i >> 6;
        int j = bij % 14; int bi = bij / 14; int irow = bi % 14; int b = bi / 14;
        float c1v = bf2f_(newvb[((size_t)bij*9 + 4)*64 + d]) + SC[NVB_OFF + d*9 + 4];
        float c3v = SC[SVB_OFF + d];
        #pragma unroll
        for (int p = 0; p < 9; p++) {
            int h1 = p % 3, h2 = p / 3;
            int y = irow + h1 - 1, xx = j + h2 - 1;
            if (y >= 0 && y < 14 && xx >= 0 && xx < 14)
                c3v += bf2f_(newvb[(((size_t)b*NP_ + y*14 + xx)*9 + p)*64 + d]);
        }
        c13bf[(size_t)bij*128 + d]      = bfr_(c1v);
        c13bf[(size_t)bij*128 + 64 + d] = bfr_(c3v);
        s1 += c1v; q1 += c1v*c1v; s3 += c3v; q3 += c3v*c3v;
    }
    sd1[tid] = s1; sq1[tid] = q1; sd3[tid] = s3; sq3[tid] = q3;
    __syncthreads();
    if (tid < 64) {
        part[blockIdx.x*256 + tid]       = sd1[tid]+sd1[tid+64]+sd1[tid+128]+sd1[tid+192];
        part[blockIdx.x*256 + 64 + tid]  = sq1[tid]+sq1[tid+64]+sq1[tid+128]+sq1[tid+192];
        part[blockIdx.x*256 + 128 + tid] = sd3[tid]+sd3[tid+64]+sd3[tid+128]+sd3[tid+192];
        part[blockIdx.x*256 + 192 + tid] = sq3[tid]+sq3[tid+64]+sq3[tid+128]+sq3[tid+192];
    }
}

// ---------------- reduce both BN stats -> scale/offset pairs ----------------
__global__ void bnreduce2_kernel(const float* __restrict__ part,
                                 const float* __restrict__ g1, const float* __restrict__ b1,
                                 const float* __restrict__ g3, const float* __restrict__ b3,
                                 float* __restrict__ stats)
{
    __shared__ float red[256];
    int t = threadIdx.x;  // 256
    float s = 0.f;
    for (int i = 0; i < 256; i++) s += part[i*256 + t];
    red[t] = s;
    __syncthreads();
    const float invN = 1.0f/12544.0f;
    if (t < 64) {
        float mean = red[t]*invN;
        float var  = red[64+t]*invN - mean*mean;
        float sc = rsqrtf(var + BN_EPS_) * g1[t];
        stats[t]      = sc;
        stats[64+t]   = b1[t] - mean*sc;
    } else if (t < 128) {
        int d = t - 64;
        float mean = red[128+d]*invN;
        float var  = red[192+d]*invN - mean*mean;
        float sc = rsqrtf(var + BN_EPS_) * g3[d];
        stats[128+d]  = sc;
        stats[192+d]  = b3[d] - mean*sc;
    }
}

// ---------------- BN apply + relu -> act13 (bf16, M_TOK layout, cls rows = 0) ----------------
__global__ __launch_bounds__(256) void bnapply13_kernel(
    const unsigned short* __restrict__ c13bf, const float* __restrict__ stats,
    unsigned short* __restrict__ msa2)
{
    int idx = blockIdx.x*256 + threadIdx.x;
    if (idx >= M_TOK*128) return;
    int k = idx & 127; int row = idx >> 7;
    int b = row / N_; int n = row - b*N_;
    float val = 0.f;
    if (n > 0) {
        float v = bf2f_(c13bf[(size_t)(b*NP_ + n - 1)*128 + k]);
        float sc, off;
        if (k < 64) { sc = stats[k]; off = stats[64+k]; }
        else        { sc = stats[64+k]; off = stats[128+k]; }
        val = fmaxf(v*sc + off, 0.f);
    }
    msa2[(size_t)row*K2P_ + 768 + k] = bfr_(val);
}

// ---------------- combined proj weights: Wp[c][0:768]=w0*proj_w, [768:896]=Wc ----------------
__global__ __launch_bounds__(256) void w13_kernel(
    const float* __restrict__ proj_w, const float* __restrict__ SC,
    unsigned short* __restrict__ Wp)
{
    int idx = blockIdx.x*256 + threadIdx.x;
    if (idx >= 768*K2P_) return;
    int k = idx % K2P_, c = idx / K2P_;
    float s;
    if (k < 768) {
        s = SC[0] * proj_w[(size_t)c*768 + k];
    } else {
        int d2 = k - 768;
        s = 0.f;
        if (d2 < 64) {
            #pragma unroll
            for (int h = 0; h < 12; h++)
                s += proj_w[(size_t)c*768 + h*64 + d2] * SC[HP_OFF + h*9 + 4];
            s *= SC[2];   // w2 * W1
        } else {
            int dd = d2 - 64;
            #pragma unroll
            for (int h = 0; h < 12; h++)
                s += proj_w[(size_t)c*768 + h*64 + dd] * SC[HPROW_OFF + h];
            s *= SC[1];   // w1 * W3
        }
    }
    Wp[(size_t)c*K2P_ + k] = bfr_(s);
}

// ---------------- launch ----------------
extern "C" void kernel_launch(void* const* d_in, const int* in_sizes, int n_in,
                              void* d_out, int out_size, void* d_ws, size_t ws_size,
                              hipStream_t stream)
{
    const float* x        = (const float*)d_in[0];
    const float* uniforms = (const float*)d_in[1];
    const float* qk_w     = (const float*)d_in[2];
    const float* qk_b     = (const float*)d_in[3];
    const float* v_w      = (const float*)d_in[4];
    const float* v_b      = (const float*)d_in[5];
    const float* proj_w   = (const float*)d_in[6];
    const float* proj_b   = (const float*)d_in[7];
    const float* bn1_g    = (const float*)d_in[8];
    const float* bn1_b    = (const float*)d_in[9];
    const float* bn3_g    = (const float*)d_in[10];
    const float* bn3_b    = (const float*)d_in[11];
    const float* kth      = (const float*)d_in[12];
    const float* head_probs = (const float*)d_in[13];
    float* out = (float*)d_out;

    // ws regions; every alias written-in-full (or written-then-read) in order each call
    float* ws = (float*)d_ws;
    float* R1 = ws;                     // 19,365,888 floats
    float* R2 = ws + 19365888;          //  9,682,944 floats
    float* R3 = ws + 29048832;          //  9,682,944 floats
    float* SC = ws + 38731776;          //    132,096 floats
    unsigned short* qkbf = (unsigned short*)R1;
    unsigned short* vbfT = (unsigned short*)R1 + 19365888;
    unsigned short* newvb = (unsigned short*)R1;
    unsigned short* vbf = (unsigned short*)R2;
    unsigned short* c13bf = (unsigned short*)R2;
    unsigned int*   x2   = (unsigned int*)R3;
    unsigned short* msa2 = (unsigned short*)R3;
    float* part = R3 + 6000000;
    unsigned short* Wp = (unsigned short*)(R3 + 6200000);
    unsigned int* W2a = (unsigned int*)out;
    unsigned int* W2b = (unsigned int*)out + 589824;
    float* stats = SC + STATS_OFF;

    prep_kernel<<<1, 256, 0, stream>>>(uniforms, kth, head_probs, v_b, SC, out + OUT_MAIN);

    conv_all<<<5592, 256, 0, stream>>>(x, qk_w, v_w, x2, W2a, W2b);

    gemm_qkv<<<1782, 256, 0, stream>>>((const unsigned short*)x2,
                                       (const unsigned short*)W2a, qk_b,
                                       qkbf, vbf, (unsigned short*)vbfT);

    flash_attn<<<768, 256, 0, stream>>>(qkbf, (const unsigned short*)vbfT, v_b, msa2);

    // conv branch chain
    newv_kernel<<<3136, 256, 0, stream>>>(vbf, SC, newvb);
    fuse13_kernel<<<256, 256, 0, stream>>>(newvb, SC, c13bf, part);
    bnreduce2_kernel<<<1, 256, 0, stream>>>(part, bn1_g, bn1_b, bn3_g, bn3_b, stats);
    bnapply13_kernel<<<6304, 256, 0, stream>>>(c13bf, stats, msa2);
    w13_kernel<<<2688, 256, 0, stream>>>(proj_w, SC, Wp);

    // proj + branch + blend -> out (K=896)
    gemm_proj<<<594, 256, 0, stream>>>(msa2, Wp, proj_b, x, SC, out);
}